// Round 2
// baseline (315.319 us; speedup 1.0000x reference)
//
#include <hip/hip_runtime.h>
#include <math.h>

#define BB 16
#define CC 256
#define HH 96
#define WW 96
#define TS 104   // LDS tile row stride (floats): 96 data + halo, keeps float4 alignment

typedef float floatx4 __attribute__((ext_vector_type(4)));  // native vec for nontemporal store

// ---------------- Kernel 1: 32x32 block-average pool -> pooled (B,C,3,3) ----
// All 9 loads issued up front (9x memory parallelism), one sync total.
__global__ __launch_bounds__(256) void pool_kernel(const float* __restrict__ x,
                                                   float* __restrict__ pooled) {
    const int bc = blockIdx.x;                       // 0 .. B*C-1
    const float4* p4 = (const float4*)(x + (size_t)bc * (HH * WW));
    const int tid  = threadIdx.x;
    const int lane = tid & 63;
    const int wv   = tid >> 6;
    const int r_in = tid >> 3;   // 0..31  row inside a 32x32 block
    const int c4   = tid & 7;    // 0..7   float4 inside the 32-wide block
    __shared__ float red[9][4];

    float s[9];
    #pragma unroll
    for (int bi = 0; bi < 3; ++bi)
        #pragma unroll
        for (int bj = 0; bj < 3; ++bj) {
            float4 v = p4[(bi * 32 + r_in) * 24 + bj * 8 + c4];
            s[bi * 3 + bj] = v.x + v.y + v.z + v.w;
        }

    #pragma unroll
    for (int k = 0; k < 9; ++k) {
        float t = s[k];
        #pragma unroll
        for (int off = 32; off; off >>= 1) t += __shfl_down(t, off, 64);
        if (lane == 0) red[k][wv] = t;
    }
    __syncthreads();
    if (tid < 9)
        pooled[bc * 9 + tid] =
            (red[tid][0] + red[tid][1] + red[tid][2] + red[tid][3]) * (1.0f / 1024.0f);
}

// ---------------- Kernel 2: MLP + softmax(G) + mix -> weight (B,C,9), bias (B,C)
__global__ __launch_bounds__(256) void proj_kernel(
    const float* __restrict__ pooled,
    const float* __restrict__ w1, const float* __restrict__ b1,
    const float* __restrict__ bn_g, const float* __restrict__ bn_b,
    const float* __restrict__ bn_m, const float* __restrict__ bn_v,
    const float* __restrict__ w2, const float* __restrict__ b2,
    const float* __restrict__ w_k, const float* __restrict__ b_k,
    float* __restrict__ weight, float* __restrict__ bias) {
    const int b = blockIdx.x / 10;
    const int p = blockIdx.x % 10;   // 0..8 = pooled pixel, 9 = global mean
    const int tid = threadIdx.x;     // == channel c in the epilogue

    __shared__ __align__(16) float t[CC];
    __shared__ __align__(16) float hbuf[64];
    __shared__ float hpart[256];

    if (p < 9) {
        t[tid] = pooled[(b * CC + tid) * 9 + p];
    } else {
        float s = 0.f;
        #pragma unroll
        for (int q = 0; q < 9; ++q) s += pooled[(b * CC + tid) * 9 + q];
        t[tid] = s * (1.0f / 9.0f);
    }
    __syncthreads();

    // h = w1 @ t  (64 outputs, 4 partial-threads each), float4 dots
    const int o = tid & 63, part = tid >> 6;
    {
        const float4* w1r = (const float4*)(w1 + o * CC + part * 64);
        const float4* tp  = (const float4*)(t + part * 64);
        float acc = 0.f;
        #pragma unroll
        for (int k = 0; k < 16; ++k) {
            float4 a = w1r[k], v = tp[k];
            acc += a.x * v.x + a.y * v.y + a.z * v.z + a.w * v.w;
        }
        hpart[tid] = acc;
    }
    __syncthreads();
    if (tid < 64) {
        float hsum = hpart[tid] + hpart[tid + 64] + hpart[tid + 128] +
                     hpart[tid + 192] + b1[tid];
        float hn = (hsum - bn_m[tid]) * (bn_g[tid] * rsqrtf(bn_v[tid] + 1e-5f)) + bn_b[tid];
        hbuf[tid] = 0.5f * hn * (1.0f + erff(hn * 0.70710678118654752f));
    }
    __syncthreads();

    float vals[4];
    #pragma unroll
    for (int q = 0; q < 4; ++q) {
        const int j = q * 256 + tid;
        const float4* w2r = (const float4*)(w2 + j * 64);
        const float4* hb  = (const float4*)hbuf;
        float a = b2[j];
        #pragma unroll
        for (int k = 0; k < 16; ++k) {
            float4 wv = w2r[k], hv = hb[k];
            a += wv.x * hv.x + wv.y * hv.y + wv.z * hv.z + wv.w * hv.w;
        }
        vals[q] = a;
    }
    float m = fmaxf(fmaxf(vals[0], vals[1]), fmaxf(vals[2], vals[3]));
    float e[4], sum = 0.f;
    #pragma unroll
    for (int q = 0; q < 4; ++q) { e[q] = expf(vals[q] - m); sum += e[q]; }
    const float rinv = 1.0f / sum;

    if (p < 9) {
        float ws = 0.f;
        #pragma unroll
        for (int q = 0; q < 4; ++q)
            ws += (e[q] * rinv) * w_k[(q * CC + tid) * 9 + p];
        weight[(b * CC + tid) * 9 + p] = ws;
    } else {
        float bs = 0.f;
        #pragma unroll
        for (int q = 0; q < 4; ++q)
            bs += (e[q] * rinv) * b_k[q * CC + tid];
        bias[b * CC + tid] = bs;
    }
}

// ---------------- Kernel 3: dynamic depthwise 3x3 conv (SAME) + bias ---------
// HALF-PLANE blocks: 2 blocks per (b,c) plane, 48 output rows each.
// LDS tile 50 rows x TS stride = 20,800 B -> 7 workgroups/CU (was 40,768 B -> 4),
// doubling the block-level load/compute pipelining depth and halving the
// barrier scope. Each thread computes a 4x4 pixel patch: 6x(b128 + 2 b32) LDS
// reads per 16 pixels. Output stores are nontemporal (out is never re-read;
// keep x resident in L2/L3 instead).
__global__ __launch_bounds__(256) void dwconv_kernel(
    const float* __restrict__ x, const float* __restrict__ weight,
    const float* __restrict__ bias, float* __restrict__ out) {
    const int bc   = blockIdx.x >> 1;
    const int half = blockIdx.x & 1;
    const int r0   = half * 48;                      // first output row of this block
    const float* plane = x + (size_t)bc * (HH * WW);
    float* oplane = out + (size_t)bc * (HH * WW);
    __shared__ __align__(16) float tile[50 * TS];
    const int tid = threadIdx.x;

    // zero the halo cells the stencil can touch:
    //   left/right halo cols for all 50 tile rows, plus the one out-of-image row
    if (tid < 50) {
        tile[tid * TS + 3]   = 0.f;      // left halo col  (c = -1)
        tile[tid * TS + 100] = 0.f;      // right halo col (c = 96)
    }
    if (tid < 98)
        tile[(half ? 49 * TS : 0) + 3 + tid] = 0.f;  // top (h=-1) or bottom (h=96) halo row

    // per-(b,c) kernel + bias (block-uniform)
    float wgt[9];
    #pragma unroll
    for (int k = 0; k < 9; ++k) wgt[k] = weight[bc * 9 + k];
    const float bs = bias[bc];

    // stage 49 global rows into the tile (float4, all 16B-aligned)
    // tile row = (global row) - r0 + 1
    {
        const int gstart = half ? 47 : 0;   // first global row staged
        const int trow0  = half ? 0 : 1;    // its tile row
        const float4* p4 = (const float4*)plane + gstart * 24;
        float4* t4 = (float4*)tile + trow0 * (TS / 4);
        #pragma unroll
        for (int i = 0; i < 5; ++i) {
            const int idx4 = tid + 256 * i;          // need 0..1175 (49 rows * 24 f4)
            if (idx4 < 1176) {
                const int r  = idx4 / 24;
                const int c4 = idx4 - r * 24;
                t4[r * (TS / 4) + 1 + c4] = p4[r * 24 + c4];
            }
        }
    }
    __syncthreads();

    // 4x4 patches: 12x24 = 288 per half-plane
    #pragma unroll
    for (int j = 0; j < 2; ++j) {
        const int pidx = tid + 256 * j;
        if (pidx < 288) {
            const int pr = pidx / 24;        // patch row 0..11
            const int pc = pidx - pr * 24;   // patch col 0..23
            const int h0 = pr * 4;           // first output row (local)
            const int cb = 4 + pc * 4;       // tile col of first pixel

            // local input rows h0-1 .. h0+4 = tile rows h0 .. h0+5
            float4 m[6]; float L[6], R[6];
            #pragma unroll
            for (int r = 0; r < 6; ++r) {
                const int a = (h0 + r) * TS + cb;
                m[r] = *(const float4*)(tile + a);
                L[r] = tile[a - 1];
                R[r] = tile[a + 4];
            }
            #pragma unroll
            for (int orow = 0; orow < 4; ++orow) {
                floatx4 acc = {bs, bs, bs, bs};
                #pragma unroll
                for (int r = 0; r < 3; ++r) {
                    const int rr = orow + r;
                    const float wl = wgt[r * 3 + 0], wc = wgt[r * 3 + 1],
                                wr = wgt[r * 3 + 2];
                    acc.x += wl * L[rr]   + wc * m[rr].x + wr * m[rr].y;
                    acc.y += wl * m[rr].x + wc * m[rr].y + wr * m[rr].z;
                    acc.z += wl * m[rr].y + wc * m[rr].z + wr * m[rr].w;
                    acc.w += wl * m[rr].z + wc * m[rr].w + wr * R[rr];
                }
                __builtin_nontemporal_store(
                    acc, (floatx4*)(oplane + (r0 + h0 + orow) * 96 + (cb - 4)));
            }
        }
    }
}

extern "C" void kernel_launch(void* const* d_in, const int* in_sizes, int n_in,
                              void* d_out, int out_size, void* d_ws, size_t ws_size,
                              hipStream_t stream) {
    const float* x    = (const float*)d_in[0];
    const float* w_k  = (const float*)d_in[1];
    const float* b_k  = (const float*)d_in[2];
    const float* w1   = (const float*)d_in[3];
    const float* b1   = (const float*)d_in[4];
    const float* bn_g = (const float*)d_in[5];
    const float* bn_b = (const float*)d_in[6];
    const float* bn_m = (const float*)d_in[7];
    const float* bn_v = (const float*)d_in[8];
    const float* w2   = (const float*)d_in[9];
    const float* b2   = (const float*)d_in[10];
    float* out = (float*)d_out;

    float* pooled = (float*)d_ws;                 // B*C*9 floats
    float* weight = pooled + BB * CC * 9;         // B*C*9 floats
    float* bias   = weight + BB * CC * 9;         // B*C   floats

    pool_kernel<<<BB * CC, 256, 0, stream>>>(x, pooled);
    proj_kernel<<<BB * 10, 256, 0, stream>>>(pooled, w1, b1, bn_g, bn_b, bn_m,
                                             bn_v, w2, b2, w_k, b_k, weight, bias);
    dwconv_kernel<<<BB * CC * 2, 256, 0, stream>>>(x, weight, bias, out);
}